// Round 5
// baseline (196.828 us; speedup 1.0000x reference)
//
#include <hip/hip_runtime.h>
#include <stdint.h>

#define N_ROWS  8192   // B*S = 4*2048
#define DIM     256
#define K_CODES 8192
#define SPLITK  16
#define KS      512           // codes per split
#define NT      128           // codes per K-tile
#define LSLOTS  16            // per-row append slots in LDS
#define GSLOTS  8             // per-row-split survivor slots in ws
// acc-space (dot) margin: covers dist-bucket/2 (1.5e-5) + 2*bf16 dot err max
// (~4.5e-5) + dropped cnorm/2 (1.9e-6). 1e-4 leaves ~1.6x slack.
#define MARGIN_ACC 1.0e-4f

typedef unsigned long long u64;
typedef unsigned short u16;
typedef short s16x8 __attribute__((ext_vector_type(8)));   // 8 bf16 = 4 VGPR
typedef float f32x4 __attribute__((ext_vector_type(4)));

__device__ __forceinline__ u64 u64min(u64 a, u64 b) { return a < b ? a : b; }

// float -> bf16 bits, round-to-nearest-even (no NaN inputs here)
__device__ __forceinline__ u16 f2bf(float f) {
    unsigned u = __float_as_uint(f);
    u += 0x7fffu + ((u >> 16) & 1u);
    return (u16)(u >> 16);
}

// async 16B global->LDS (dest = wave-uniform base + lane*16, HW-added)
__device__ __forceinline__ void gld16(void* lds, const void* g) {
    __builtin_amdgcn_global_load_lds(
        (const __attribute__((address_space(1))) unsigned int*)g,
        (__attribute__((address_space(3))) unsigned int*)lds, 16, 0, 0);
}

// Raw s_barrier with compiler memory fences on BOTH sides (naked builtin
// does not order memory at the compiler level).
__device__ __forceinline__ void block_barrier() {
    asm volatile("" ::: "memory");
    __builtin_amdgcn_s_barrier();
    asm volatile("" ::: "memory");
}

// ---------------------------------------------------------------- kernel A
// Fused: bf16 conversion of z_e & cb + row norms. One wave per row.
__global__ __launch_bounds__(256) void vq_prep(const float* __restrict__ z_e,
                                               const float* __restrict__ cb,
                                               u16* __restrict__ zb,
                                               u16* __restrict__ cbb,
                                               float* __restrict__ xnorm,
                                               float* __restrict__ cnorm) {
    int wid  = (blockIdx.x * 256 + threadIdx.x) >> 6;
    int lane = threadIdx.x & 63;
    const float* src; u16* d16; float* dn;
    if (wid < N_ROWS) { src = z_e + (size_t)wid * DIM; d16 = zb + (size_t)wid * DIM; dn = xnorm + wid; }
    else              { int k = wid - N_ROWS;
                        src = cb  + (size_t)k   * DIM; d16 = cbb + (size_t)k * DIM; dn = cnorm + k; }
    float4 v = *(const float4*)(src + lane * 4);
    ushort4 h;
    h.x = f2bf(v.x); h.y = f2bf(v.y); h.z = f2bf(v.z); h.w = f2bf(v.w);
    *(ushort4*)(d16 + lane * 4) = h;
    float s = (v.x * v.x + v.y * v.y) + (v.z * v.z + v.w * v.w);
#pragma unroll
    for (int off = 1; off < 64; off <<= 1)
        s += __shfl_xor(s, off, 64);
    if (lane == 0) *dn = s;
}

// ---------------------------------------------------------------- kernel B
// bf16 MFMA dot GEMM + per-row running MAX of dot (argmin dist == argmax dot;
// xnorm constant per row, cnorm<=3.8e-6 folded into margin) + margin-append.
// Block: 128 rows x 512 codes (one split), 4 waves, each a 32-row slab.
//
// Pipeline (R5 correctness-hardened):
//  * SPLITK 16: 4096 waves -> up to 12 waves/CU at zero extra LDS traffic.
//  * A (32 rows, full K=256) in registers: af[2][8] = 64 VGPR, loaded once.
//  * C staged into a 4-deep ring of 8 KB half-tiles (64 codes x 64 dims,
//    128B-row XOR swizzle, 2-way-free banking). 32 phases/block, each:
//      vmcnt(4) lgkmcnt(0) -> BARRIER -> STAGE(p+3) -> 8x ds_read_b128 -> 16 MFMA
//  * R5 fix 1: __launch_bounds__(256,2) NOT (256,3). The 170-reg squeeze
//    spilled, and scratch buffer-ops count in vmcnt -> the hand-counted
//    vmcnt(4) window retired spill ops instead of stage(p) -> PHASE read a
//    half-staged slot (R3/R4 nondeterministic index corruption). At ~130
//    VGPR natural, 3 blocks/CU still achieved via LDS (50.7 KB).
//  * R5 fix 2: every pre-barrier wait also drains lgkmcnt(0). The fences
//    order ds_reads before the barrier at COMPILE time, but the MFMAs
//    consuming them are register-only and may be sunk below the barrier
//    (with their lgkmcnt waits) -> a wave could cross the barrier with
//    reads in flight while another wave's STAGE overwrite lands. The
//    explicit lgkmcnt(0) makes the drain a RUNTIME guarantee.
__global__ __launch_bounds__(256, 2) void vq_mfma(const u16* __restrict__ zb,
                                                  const u16* __restrict__ cbb,
                                                  int* __restrict__ cand_cnt,
                                                  int* __restrict__ cand_idx) {
    __shared__ u16   Cs[4][64 * 64];   // 32 KB ring: 4 x (64 code-rows x 64 dims), swizzled
    __shared__ float lcd[128 * LSLOTS];
    __shared__ int   lci[128 * LSLOTS];
    __shared__ int   lcnt[128];
    __shared__ float gmaxs[128];

    const int tid   = threadIdx.x;
    const int lane  = tid & 63;
    const int wave  = tid >> 6;
    const int quad  = lane >> 4;
    const int l16   = lane & 15;
    const int split = blockIdx.x;
    const int n0    = blockIdx.y * 128;

    if (tid < 128) lcnt[tid] = 0;

    // staging lane constants: lane covers (row srow8 of 8-group, dest chunk schunk)
    const int srow8  = lane >> 3;
    const int schunk = lane & 7;
    const int ssw    = (schunk ^ srow8) * 8;   // swizzled source chunk offset (shorts)
    const u16* csrc  = cbb + (size_t)split * KS * DIM + (size_t)srow8 * DIM + ssw;

    // ---- A fragments in registers. af[i][s]: row n0+wave*32+i*16+l16,
    // dims s*32 + quad*8 .. +7   (s = kc*2+ks)
    s16x8 af[2][8];
#pragma unroll
    for (int i = 0; i < 2; i++) {
        const u16* p = zb + (size_t)(n0 + wave * 32 + i * 16 + l16) * DIM + quad * 8;
#pragma unroll
        for (int s = 0; s < 8; s++)
            af[i][s] = *(const s16x8*)(p + s * 32);
    }

    // stage half-tile s (kt=s>>3; code-half s&1; dims-chunk (s>>1)&3)
    // into ring slot. Per wave: 2 gld16 covering code-row-groups wave*2+t.
    auto STAGE = [&](int s, int slot) {
        const int kts = s >> 3, pls = s & 7;
        const u16* src = csrc + (size_t)(kts * NT + (pls & 1) * 64) * DIM + (pls >> 1) * 64;
#pragma unroll
        for (int t = 0; t < 2; t++) {
            int rg = wave * 2 + t;            // 8-code-row group, wave-uniform
            gld16(&Cs[slot][rg * 512], src + (size_t)rg * (8 * DIM));
        }
    };

    f32x4 acc[2][8];
    float runmax[8];
#pragma unroll
    for (int t = 0; t < 8; t++) runmax[t] = -3.0e38f;

    // compute phase pl of the current kt: reads ring slot pl&3 (code-half
    // pl&1, dims-chunk pl>>1), 8 ds_read_b128 + 16 MFMA.
    auto PHASE = [&](int pl) {
        const u16* cbuf = &Cs[pl & 3][0];
#pragma unroll
        for (int ks = 0; ks < 2; ks++) {
            s16x8 bfr[4];
#pragma unroll
            for (int jj = 0; jj < 4; jj++)
                bfr[jj] = *(const s16x8*)&cbuf[(jj * 16 + l16) * 64 +
                                               (((ks << 2) | quad) ^ (l16 & 7)) * 8];
#pragma unroll
            for (int i = 0; i < 2; i++)
#pragma unroll
                for (int jj = 0; jj < 4; jj++)
                    acc[i][(pl & 1) * 4 + jj] = __builtin_amdgcn_mfma_f32_16x16x32_bf16(
                        af[i][(pl >> 1) * 2 + ks], bfr[jj], acc[i][(pl & 1) * 4 + jj], 0, 0, 0);
        }
    };

    // per-kt epilogue: in-wave row max over 8 code-frags, runmax update,
    // margin appends. Row rl = wave*32 + i*16 + quad*4 + r (wave-owned).
    auto EPILOGUE = [&](int kbase) {
#pragma unroll
        for (int i = 0; i < 2; i++)
#pragma unroll
            for (int r = 0; r < 4; r++) {
                float m = fmaxf(fmaxf(fmaxf(acc[i][0][r], acc[i][1][r]),
                                      fmaxf(acc[i][2][r], acc[i][3][r])),
                                fmaxf(fmaxf(acc[i][4][r], acc[i][5][r]),
                                      fmaxf(acc[i][6][r], acc[i][7][r])));
                m = fmaxf(m, __shfl_xor(m, 1, 64));
                m = fmaxf(m, __shfl_xor(m, 2, 64));
                m = fmaxf(m, __shfl_xor(m, 4, 64));
                m = fmaxf(m, __shfl_xor(m, 8, 64));
                runmax[i * 4 + r] = fmaxf(runmax[i * 4 + r], m);
                float thr = runmax[i * 4 + r] - MARGIN_ACC;
                int rl = wave * 32 + i * 16 + quad * 4 + r;
#pragma unroll
                for (int j = 0; j < 8; j++) {
                    float d = acc[i][j][r];
                    if (d >= thr) {
                        int pos = atomicAdd(&lcnt[rl], 1);
                        if (pos < LSLOTS) {
                            lcd[rl * LSLOTS + pos] = d;
                            lci[rl * LSLOTS + pos] = kbase + j * 16 + l16;
                        }
                    }
                }
            }
    };

    // prologue: fill ring slots 0..2 (3 half-tiles ahead)
    STAGE(0, 0); STAGE(1, 1); STAGE(2, 2);

    for (int kt = 0; kt < 3; kt++) {      // kt 0..2: uniform phases
        const int kbase = split * KS + kt * NT;
#pragma unroll
        for (int i = 0; i < 2; i++)
#pragma unroll
            for (int j = 0; j < 8; j++)
#pragma unroll
                for (int e = 0; e < 4; e++) acc[i][j][e] = 0.0f;
#pragma unroll
        for (int pl = 0; pl < 8; pl++) {
            asm volatile("s_waitcnt vmcnt(4) lgkmcnt(0)" ::: "memory"); // stage(p) + own LDS ops done
            block_barrier();                                   // publish slot pl&3
            STAGE(kt * 8 + pl + 3, (pl + 3) & 3);              // slot (p-1)&3: readers drained
            PHASE(pl);
        }
        EPILOGUE(kbase);
    }
    {   // kt = 3: tail waits (no more stages after s=31)
        const int kbase = split * KS + 3 * NT;
#pragma unroll
        for (int i = 0; i < 2; i++)
#pragma unroll
            for (int j = 0; j < 8; j++)
#pragma unroll
                for (int e = 0; e < 4; e++) acc[i][j][e] = 0.0f;
#pragma unroll
        for (int pl = 0; pl < 5; pl++) {
            asm volatile("s_waitcnt vmcnt(4) lgkmcnt(0)" ::: "memory");
            block_barrier();
            STAGE(24 + pl + 3, (pl + 3) & 3);
            PHASE(pl);
        }
        asm volatile("s_waitcnt vmcnt(4) lgkmcnt(0)" ::: "memory");   // p=29: retire 29
        block_barrier();
        PHASE(5);
        asm volatile("s_waitcnt vmcnt(2) lgkmcnt(0)" ::: "memory");   // p=30: retire 30
        block_barrier();
        PHASE(6);
        asm volatile("s_waitcnt vmcnt(0) lgkmcnt(0)" ::: "memory");   // p=31
        block_barrier();
        PHASE(7);
        EPILOGUE(kbase);
    }

    if (l16 == 0) {
#pragma unroll
        for (int i = 0; i < 2; i++)
#pragma unroll
            for (int r = 0; r < 4; r++)
                gmaxs[wave * 32 + i * 16 + quad * 4 + r] = runmax[i * 4 + r];
    }
    __syncthreads();

    // filter appends vs final row max (winner guaranteed in the superset)
    if (tid < 128) {
        int n   = n0 + tid;
        int cnt = lcnt[tid]; if (cnt > LSLOTS) cnt = LSLOTS;
        float thrf = gmaxs[tid] - MARGIN_ACC;
        int base = (n * SPLITK + split) * GSLOTS;
        int w = 0;
        for (int s = 0; s < cnt && w < GSLOTS; s++)
            if (lcd[tid * LSLOTS + s] >= thrf)
                cand_idx[base + w++] = lci[tid * LSLOTS + s];
        cand_cnt[n * SPLITK + split] = w;
    }
}

// ---------------------------------------------------------------- kernel C
// Exact fp32 recheck (association identical to the R2/R3-passing version:
// sequential fmaf d=0..255, fmaf(-2,m,xn)+cn), lexicographic (dist,idx) min;
// then gather + z_q_st + rowloss. One wave per row.
__global__ __launch_bounds__(256) void vq_finalize(const float* __restrict__ z_e,
                                                   const float* __restrict__ cb,
                                                   const float* __restrict__ xnorm,
                                                   const float* __restrict__ cnorm,
                                                   const int* __restrict__ cand_cnt,
                                                   const int* __restrict__ cand_idx,
                                                   float* __restrict__ out_zq,
                                                   float* __restrict__ out_idx,
                                                   float* __restrict__ rowloss) {
    const int n    = blockIdx.x * 4 + (threadIdx.x >> 6);
    const int lane = threadIdx.x & 63;

    int myidx = -1;
    int t = 0;
#pragma unroll
    for (int s = 0; s < SPLITK; s++) {
        int c = cand_cnt[n * SPLITK + s];
        if (lane >= t && lane < t + c)
            myidx = cand_idx[(n * SPLITK + s) * GSLOTS + (lane - t)];
        t += c;
    }

    u64 key = ~0ULL;
    if (myidx >= 0) {
        const float* xr = z_e + (size_t)n * DIM;
        const float* cr = cb + (size_t)myidx * DIM;
        float acc = 0.0f;
#pragma unroll 8
        for (int d = 0; d < DIM; d++)
            acc = __builtin_fmaf(xr[d], cr[d], acc);
        float dist = __builtin_fmaf(-2.0f, acc, xnorm[n]) + cnorm[myidx];
        key = ((u64)__float_as_uint(dist) << 32) | (unsigned)myidx;
    }
#pragma unroll
    for (int off = 1; off < 64; off <<= 1)
        key = u64min(key, __shfl_xor(key, off, 64));

    int idx = (int)(unsigned)(key & 0xffffffffu);
    if (key == ~0ULL) idx = 0;  // unreachable safety

    float4 x = *(const float4*)(z_e + (size_t)n * DIM + lane * 4);
    float4 c = *(const float4*)(cb + (size_t)idx * DIM + lane * 4);
    float4 st;
    st.x = x.x + (c.x - x.x); st.y = x.y + (c.y - x.y);
    st.z = x.z + (c.z - x.z); st.w = x.w + (c.w - x.w);
    *(float4*)(out_zq + (size_t)n * DIM + lane * 4) = st;

    float d0 = x.x - c.x, d1 = x.y - c.y, d2 = x.z - c.z, d3 = x.w - c.w;
    float s2 = (d0 * d0 + d1 * d1) + (d2 * d2 + d3 * d3);
#pragma unroll
    for (int off = 1; off < 64; off <<= 1)
        s2 += __shfl_xor(s2, off, 64);
    if (lane == 0) {
        rowloss[n] = s2;
        out_idx[n] = (float)idx;
    }
}

// ---------------------------------------------------------------- kernel D
__global__ __launch_bounds__(256) void vq_loss(const float* __restrict__ rowloss,
                                               float* __restrict__ out_loss) {
    __shared__ double sd[256];
    double s = 0.0;
    for (int i = threadIdx.x; i < N_ROWS; i += 256) s += (double)rowloss[i];
    sd[threadIdx.x] = s;
    __syncthreads();
    for (int off = 128; off; off >>= 1) {
        if (threadIdx.x < off) sd[threadIdx.x] += sd[threadIdx.x + off];
        __syncthreads();
    }
    if (threadIdx.x == 0) {
        double mean = sd[0] / (double)((size_t)N_ROWS * DIM);
        out_loss[0] = (float)(1.25 * mean);
    }
}

// ---------------------------------------------------------------- launch
extern "C" void kernel_launch(void* const* d_in, const int* in_sizes, int n_in,
                              void* d_out, int out_size, void* d_ws, size_t ws_size,
                              hipStream_t stream) {
    const float* z_e = (const float*)d_in[0];
    const float* cb  = (const float*)d_in[1];

    float* out   = (float*)d_out;
    float* zq    = out;
    float* oidx  = out + (size_t)N_ROWS * DIM;
    float* oloss = oidx + N_ROWS;

    // ws layout (~12.6 MB):
    //   zb   bf16[8192*256]  4 MB
    //   cbb  bf16[8192*256]  4 MB
    //   xnorm/cnorm/rowloss  3*32 KB
    //   cand_cnt int[8192*16] 512 KB
    //   cand_idx int[8192*16*GSLOTS] 4 MB
    u16*   zb       = (u16*)d_ws;
    u16*   cbb      = zb + (size_t)N_ROWS * DIM;
    float* xnorm    = (float*)(cbb + (size_t)K_CODES * DIM);
    float* cnorm    = xnorm + N_ROWS;
    float* rowloss  = cnorm + K_CODES;
    int*   cand_cnt = (int*)(rowloss + N_ROWS);
    int*   cand_idx = cand_cnt + N_ROWS * SPLITK;

    vq_prep    <<<(N_ROWS + K_CODES) / 4, 256, 0, stream>>>(z_e, cb, zb, cbb, xnorm, cnorm);
    // grid (split, mtile): linear%8 == split%8 -> splits s and s+8 pinned to
    // one XCD; 0.5MB bf16 codebook halves + zb rows stay L2-resident.
    vq_mfma    <<<dim3(SPLITK, N_ROWS / 128), 256, 0, stream>>>(zb, cbb, cand_cnt, cand_idx);
    vq_finalize<<<N_ROWS / 4, 256, 0, stream>>>(z_e, cb, xnorm, cnorm, cand_cnt, cand_idx, zq, oidx, rowloss);
    vq_loss    <<<1, 256, 0, stream>>>(rowloss, oloss);
}